// Round 12
// baseline (1254.830 us; speedup 1.0000x reference)
//
#include <hip/hip_runtime.h>

#define D 300
#define KP 320
#define NPAD 50048
#define NTILES 782      // NPAD/64
#define TPB 2           // row-tiles per gemm block
#define NRB 391         // row-blocks (NTILES/TPB)
#define RBX 49          // row-blocks per XCD (8*49=392 >= 391)
#define WSTRIDE 328     // LDS k-stride (u16): 164 words, %32=4 -> 2-way banks (free)
#define NGR 256
#define NL 5
#define NC 128
#define BN_EPS 1e-5f

typedef __attribute__((ext_vector_type(8))) short bf16x8;
typedef __attribute__((ext_vector_type(4))) float f32x4;
typedef unsigned short u16;

__device__ __forceinline__ void atomAdd(float* p, float v) { unsafeAtomicAdd(p, v); }

__device__ __forceinline__ short f2bf(float f) {
    union { float f; unsigned u; } v; v.f = f;
    unsigned r = v.u + 0x7fffu + ((v.u >> 16) & 1u);   // RNE
    return (short)(r >> 16);
}
__device__ __forceinline__ float bf2f(short s) {
    union { unsigned u; float f; } v;
    v.u = ((unsigned)(u16)s) << 16;
    return v.f;
}
// HW packed f32x2 -> bf16x2 (RNE). 1 VALU op per 2 elements vs 5/element manual.
__device__ __forceinline__ unsigned pkbf(float a, float b) {
    unsigned r;
    asm("v_cvt_pk_bf16_f32 %0, %1, %2" : "=v"(r) : "v"(a), "v"(b));
    return r;
}
__device__ __forceinline__ bf16x8 pack8(const float* f) {
    union { unsigned u[4]; bf16x8 v; } o;
    o.u[0] = pkbf(f[0], f[1]);
    o.u[1] = pkbf(f[2], f[3]);
    o.u[2] = pkbf(f[4], f[5]);
    o.u[3] = pkbf(f[6], f[7]);
    return o.v;
}

// ---------------------------------------------------------------------------
// offsets: off[g] = lower_bound(batch, g)
// ---------------------------------------------------------------------------
__global__ void offsets_kernel(const int* __restrict__ batch, int* __restrict__ off, int N) {
    int g = threadIdx.x;
    if (g > NGR) return;
    int lo = 0, hi = N;
    while (lo < hi) {
        int mid = (lo + hi) >> 1;
        if (batch[mid] < g) lo = mid + 1; else hi = mid;
    }
    off[g] = lo;
}

// ---------------------------------------------------------------------------
// CSR build: deg histogram -> hierarchical scan -> slot fill
// ---------------------------------------------------------------------------
__global__ __launch_bounds__(256)
void deg_kernel(const int* __restrict__ ei, int* __restrict__ deg, int E) {
    int e = blockIdx.x * 256 + threadIdx.x;
    if (e < E) atomicAdd(&deg[ei[E + e]], 1);
}

__global__ __launch_bounds__(256)
void degpart_kernel(const int* __restrict__ deg, int* __restrict__ part, int N) {
    int i = blockIdx.x * 256 + threadIdx.x;
    int v = (i < N) ? deg[i] : 0;
    #pragma unroll
    for (int o = 1; o < 64; o <<= 1) v += __shfl_xor(v, o);
    __shared__ int ws[4];
    if ((threadIdx.x & 63) == 0) ws[threadIdx.x >> 6] = v;
    __syncthreads();
    if (threadIdx.x == 0) part[blockIdx.x] = ws[0] + ws[1] + ws[2] + ws[3];
}

__global__ __launch_bounds__(256)
void partscan_kernel(int* __restrict__ part, int nb) {   // 1 block; nb <= 256
    __shared__ int buf[256];
    int t = threadIdx.x;
    int v = (t < nb) ? part[t] : 0;
    buf[t] = v;
    __syncthreads();
    for (int o = 1; o < 256; o <<= 1) {
        int u = (t >= o) ? buf[t - o] : 0;
        __syncthreads();
        buf[t] += u;
        __syncthreads();
    }
    if (t < nb) part[t] = (t == 0) ? 0 : buf[t - 1];   // exclusive
}

__global__ __launch_bounds__(256)
void rowptr_kernel(const int* __restrict__ deg, const int* __restrict__ part,
                   int* __restrict__ rowptr, int N, int E) {
    __shared__ int buf[256];
    int b = blockIdx.x, t = threadIdx.x;
    int i = b * 256 + t;
    int v = (i < N) ? deg[i] : 0;
    buf[t] = v;
    __syncthreads();
    for (int o = 1; o < 256; o <<= 1) {
        int u = (t >= o) ? buf[t - o] : 0;
        __syncthreads();
        buf[t] += u;
        __syncthreads();
    }
    if (i < N) rowptr[i] = part[b] + buf[t] - v;
    if (b == 0 && t == 0) rowptr[N] = E;
}

__global__ __launch_bounds__(256)
void fill_kernel(const int* __restrict__ ei, const int* __restrict__ rowptr,
                 int* __restrict__ cursor, int* __restrict__ col, int E) {
    int e = blockIdx.x * 256 + threadIdx.x;
    if (e >= E) return;
    int src = ei[e];
    int dst = ei[E + e];
    int pos = atomicAdd(&cursor[dst], 1);
    col[rowptr[dst] + pos] = src;
}

// ---------------------------------------------------------------------------
// weight convert: Wt[mat][n (320)][k (320)] = bf16(W[k][n]); pads zero
// ---------------------------------------------------------------------------
__global__ __launch_bounds__(256)
void wcvt_kernel(const float* __restrict__ W1, const float* __restrict__ W2,
                 u16* __restrict__ Wt) {
    int idx = blockIdx.x * 256 + threadIdx.x;
    if (idx >= 10 * KP * 80) return;
    int n4 = idx % 80;
    int k = (idx / 80) % KP;
    int mat = idx / (80 * KP);
    const float* Wsrc = (mat < NL) ? (W1 + (size_t)mat * D * D) : (W2 + (size_t)(mat - NL) * D * D);
    float4 w = make_float4(0.f, 0.f, 0.f, 0.f);
    if (k < D && n4 < 75) w = *(const float4*)(Wsrc + (size_t)k * D + n4 * 4);
    size_t base = ((size_t)mat * 320 + n4 * 4) * KP + k;
    Wt[base]          = (u16)f2bf(w.x);
    Wt[base + KP]     = (u16)f2bf(w.y);
    Wt[base + 2 * KP] = (u16)f2bf(w.z);
    Wt[base + 3 * KP] = (u16)f2bf(w.w);
}

// ---------------------------------------------------------------------------
// x convert: xbf[row][c] = bf16(x[row][c]), pads (c>=300, row>=N) zero
// ---------------------------------------------------------------------------
__global__ __launch_bounds__(256)
void xcvt_kernel(const float* __restrict__ x, u16* __restrict__ xbf, int N) {
    int idx = blockIdx.x * 256 + threadIdx.x;
    if (idx >= NPAD * 40) return;
    int row = idx / 40;
    int c8 = (idx - row * 40) * 8;
    short o[8];
    #pragma unroll
    for (int i = 0; i < 8; ++i) {
        int c = c8 + i;
        float f = (row < N && c < D) ? x[(size_t)row * D + c] : 0.f;
        o[i] = f2bf(f);
    }
    *(bf16x8*)(xbf + (size_t)row * KP + c8) = *(bf16x8*)o;
}

// ---------------------------------------------------------------------------
// gather with fused BN2+ReLU on source rows; edge loop unrolled x2.
// ---------------------------------------------------------------------------
template<bool APPLY>
__global__ __launch_bounds__(256)
void gather_kernel(const u16* __restrict__ H, u16* __restrict__ Z,
                   const int* __restrict__ rowptr, const int* __restrict__ col,
                   const float* __restrict__ scsh, int N) {
    int idx = blockIdx.x * 256 + threadIdx.x;
    if (idx >= N * 40) return;
    int node = idx / 40;
    int c8 = (idx - node * 40) * 8;
    float sc[8], sh[8];
    if (APPLY) {
        #pragma unroll
        for (int i = 0; i < 8; ++i) { sc[i] = scsh[c8 + i]; sh[i] = scsh[KP + c8 + i]; }
    }
    int s = rowptr[node], e = rowptr[node + 1];
    bf16x8 v = *(const bf16x8*)(H + (size_t)node * KP + c8);
    float acc[8];
    #pragma unroll
    for (int i = 0; i < 8; ++i) {
        float f = bf2f(v[i]);
        acc[i] = APPLY ? fmaxf(fmaf(f, sc[i], sh[i]), 0.f) : f;
    }
    int j = s;
    for (; j + 2 <= e; j += 2) {
        int s0 = col[j], s1 = col[j + 1];
        bf16x8 w0 = *(const bf16x8*)(H + (size_t)s0 * KP + c8);
        bf16x8 w1 = *(const bf16x8*)(H + (size_t)s1 * KP + c8);
        #pragma unroll
        for (int i = 0; i < 8; ++i) {
            float f0 = bf2f(w0[i]);
            float f1 = bf2f(w1[i]);
            acc[i] += APPLY ? fmaxf(fmaf(f0, sc[i], sh[i]), 0.f) : f0;
            acc[i] += APPLY ? fmaxf(fmaf(f1, sc[i], sh[i]), 0.f) : f1;
        }
    }
    if (j < e) {
        int s0 = col[j];
        bf16x8 w0 = *(const bf16x8*)(H + (size_t)s0 * KP + c8);
        #pragma unroll
        for (int i = 0; i < 8; ++i) {
            float f0 = bf2f(w0[i]);
            acc[i] += APPLY ? fmaxf(fmaf(f0, sc[i], sh[i]), 0.f) : f0;
        }
    }
    *(bf16x8*)(Z + (size_t)node * KP + c8) = pack8(acc);
}

// ---------------------------------------------------------------------------
// pool with optional fused BN2+ReLU; one block per graph, coalesced rows.
// ---------------------------------------------------------------------------
template<bool APPLY>
__global__ __launch_bounds__(320)
void pool_kernel(const u16* __restrict__ H, const int* __restrict__ off,
                 const float* __restrict__ scsh, float* __restrict__ pooled_l) {
    __shared__ float red[8][KP];
    int t = threadIdx.x;
    int g = blockIdx.x;
    int rq = t / 40;
    int c8 = (t - rq * 40) * 8;
    float sc[8], sh[8];
    if (APPLY) {
        #pragma unroll
        for (int i = 0; i < 8; ++i) { sc[i] = scsh[c8 + i]; sh[i] = scsh[KP + c8 + i]; }
    }
    int r0 = off[g], r1 = off[g + 1];
    float a[8] = {};
    for (int r = r0 + rq; r < r1; r += 8) {
        bf16x8 v = *(const bf16x8*)(H + (size_t)r * KP + c8);
        #pragma unroll
        for (int i = 0; i < 8; ++i) {
            float f = bf2f(v[i]);
            a[i] += APPLY ? fmaxf(fmaf(f, sc[i], sh[i]), 0.f) : f;
        }
    }
    #pragma unroll
    for (int i = 0; i < 8; ++i) red[rq][c8 + i] = a[i];
    __syncthreads();
    int c = t;
    if (c < D) {
        float s = 0.f;
        #pragma unroll
        for (int j = 0; j < 8; ++j) s += red[j][c];
        pooled_l[g * D + c] = s;
    }
}

// ---------------------------------------------------------------------------
// Persistent-W MFMA GEMM, XCD-swizzled 1D grid (8*RBX*4 = 1568 blocks):
//   xcd = bid&7, j = bid>>3, quarter = j/RBX, rowblock = xcd*RBX + j%RBX.
// Each XCD owns a contiguous ~4MB A-slab for ALL 4 n-quarters -> quarter
// re-reads hit that XCD's L2 (round-10 FETCH 54MB was the 4x A re-read
// crossing XCDs). Block stages its 80x320 W-slab once; zero barriers in the
// tile loop; next tile's A prefetched during current compute (latency hide).
// Packed v_cvt_pk_bf16_f32 for all f32->bf16 (round-10 VALUBusy 24% was
// dominated by 5-op manual f2bf).
// ---------------------------------------------------------------------------
template<bool APPLY>
__global__ __launch_bounds__(256)
void mfma_gemm_kernel(const u16* __restrict__ Abf, const u16* __restrict__ Wt,
                      const float* __restrict__ bias, const float* __restrict__ scsh,
                      u16* __restrict__ Cbf, float* __restrict__ stats, int Nreal) {
    const int bid = blockIdx.x;
    const int xcd = bid & 7;
    const int j = bid >> 3;
    const int quarter = j / RBX;
    const int rowblock = xcd * RBX + (j - quarter * RBX);
    if (rowblock >= NRB) return;           // uniform; 8 idle blocks
    const int nBase = quarter * 80;

    __shared__ u16 Ws[80 * WSTRIDE];       // 52.5 KB
    __shared__ float lsum[80], lsq[80];
    const int tid = threadIdx.x;

    {   // stage W quarter once: 80 n-rows x 40 bf16x8 units
        const u16* src = Wt + (size_t)nBase * KP;
        for (int unit = tid; unit < 80 * 40; unit += 256) {
            int n = unit / 40, kg = unit - n * 40;
            *(bf16x8*)&Ws[n * WSTRIDE + kg * 8] =
                *(const bf16x8*)(src + (size_t)n * KP + kg * 8);
        }
    }
    if (tid < 80) { lsum[tid] = 0.f; lsq[tid] = 0.f; }
    __syncthreads();                       // barrier 1 of 2

    const int wave = tid >> 6, lane = tid & 63;
    const int quad = lane >> 4, l16 = lane & 15;
    const int tile0 = rowblock * TPB;

    // prefetch tile 0's A
    bf16x8 a[10];
    {
        const u16* arow = Abf + (size_t)(tile0 * 64 + wave * 16 + l16) * KP + quad * 8;
        #pragma unroll
        for (int kc = 0; kc < 10; ++kc) a[kc] = *(const bf16x8*)(arow + kc * 32);
    }

    for (int t = 0; t < TPB; ++t) {
        // prefetch next tile's A while computing this one
        bf16x8 an[10];
        if (t + 1 < TPB) {
            const u16* arow = Abf + (size_t)((tile0 + t + 1) * 64 + wave * 16 + l16) * KP + quad * 8;
            #pragma unroll
            for (int kc = 0; kc < 10; ++kc) an[kc] = *(const bf16x8*)(arow + kc * 32);
        }

        if (APPLY) {
            #pragma unroll
            for (int kc = 0; kc < 10; ++kc) {
                const float* sp = scsh + kc * 32 + quad * 8;
                float4 s0 = *(const float4*)sp;
                float4 s1 = *(const float4*)(sp + 4);
                float4 h0 = *(const float4*)(sp + KP);
                float4 h1 = *(const float4*)(sp + KP + 4);
                float sc[8] = {s0.x, s0.y, s0.z, s0.w, s1.x, s1.y, s1.z, s1.w};
                float sh[8] = {h0.x, h0.y, h0.z, h0.w, h1.x, h1.y, h1.z, h1.w};
                float f[8];
                #pragma unroll
                for (int i = 0; i < 8; ++i)
                    f[i] = fmaxf(fmaf(bf2f(a[kc][i]), sc[i], sh[i]), 0.f);
                a[kc] = pack8(f);
            }
        }

        f32x4 acc[5] = {};
        #pragma unroll
        for (int kc = 0; kc < 10; ++kc) {
            #pragma unroll
            for (int nt = 0; nt < 5; ++nt) {
                bf16x8 b = *(const bf16x8*)&Ws[(nt * 16 + l16) * WSTRIDE + kc * 32 + quad * 8];
                acc[nt] = __builtin_amdgcn_mfma_f32_16x16x32_bf16(a[kc], b, acc[nt], 0, 0, 0);
            }
        }

        // epilogue
        const int rbase = (tile0 + t) * 64 + wave * 16 + quad * 4;
        #pragma unroll
        for (int nt = 0; nt < 5; ++nt) {
            int nl = nt * 16 + l16;
            int colg = nBase + nl;
            if (colg >= D) continue;
            float bia = bias[colg];
            float v0 = acc[nt][0] + bia, v1 = acc[nt][1] + bia;
            float v2 = acc[nt][2] + bia, v3 = acc[nt][3] + bia;
            float s = 0.f, q = 0.f;
            bool ok0 = rbase + 0 < Nreal, ok1 = rbase + 1 < Nreal;
            bool ok2 = rbase + 2 < Nreal, ok3 = rbase + 3 < Nreal;
            if (ok0) { s += v0; q = fmaf(v0, v0, q); }
            if (ok1) { s += v1; q = fmaf(v1, v1, q); }
            if (ok2) { s += v2; q = fmaf(v2, v2, q); }
            if (ok3) { s += v3; q = fmaf(v3, v3, q); }
            unsigned pa = pkbf(v0, v1), pb = pkbf(v2, v3);
            Cbf[(size_t)(rbase + 0) * KP + colg] = ok0 ? (u16)pa : (u16)0;
            Cbf[(size_t)(rbase + 1) * KP + colg] = ok1 ? (u16)(pa >> 16) : (u16)0;
            Cbf[(size_t)(rbase + 2) * KP + colg] = ok2 ? (u16)pb : (u16)0;
            Cbf[(size_t)(rbase + 3) * KP + colg] = ok3 ? (u16)(pb >> 16) : (u16)0;
            s += __shfl_xor(s, 16); s += __shfl_xor(s, 32);
            q += __shfl_xor(q, 16); q += __shfl_xor(q, 32);
            if (quad == 0) { atomicAdd(&lsum[nl], s); atomicAdd(&lsq[nl], q); }
        }

        if (t + 1 < TPB) {
            #pragma unroll
            for (int kc = 0; kc < 10; ++kc) a[kc] = an[kc];
        }
    }
    __syncthreads();                       // barrier 2 of 2
    if (tid < 80) {
        int colg = nBase + tid;
        if (colg < D) {
            atomAdd(&stats[colg], lsum[tid]);
            atomAdd(&stats[KP + colg], lsq[tid]);
        }
    }
}

// ---------------------------------------------------------------------------
// BN finalize; self-zeroes stats for the next GEMM
// ---------------------------------------------------------------------------
__global__ void bnfin_kernel(float* __restrict__ sums, const float* __restrict__ g,
                             const float* __restrict__ be, float* __restrict__ scsh, float invN) {
    int c = threadIdx.x;
    if (c >= D) return;
    float mu = sums[c] * invN;
    float var = sums[KP + c] * invN - mu * mu;
    float s = g[c] / sqrtf(var + BN_EPS);
    scsh[c] = s;
    scsh[KP + c] = fmaf(-mu, s, be[c]);
    sums[c] = 0.f;
    sums[KP + c] = 0.f;
}

// ---------------------------------------------------------------------------
// readout
// ---------------------------------------------------------------------------
__global__ __launch_bounds__(128)
void bias_init_kernel(const float* __restrict__ fcb, float* __restrict__ out) {
    int i = blockIdx.x * 128 + threadIdx.x;
    if (i >= NGR * NC) return;
    int c = i & (NC - 1);
    float s = 0.f;
    for (int l = 0; l <= NL; ++l) s += fcb[l * NC + c];
    out[i] = s;
}

__global__ __launch_bounds__(128)
void readout_kernel(const float* __restrict__ pooled, const int* __restrict__ off,
                    const float* __restrict__ fcW, float* __restrict__ out) {
    __shared__ float sp[4][D];
    int c = threadIdx.x;
    int l = blockIdx.y;
    int g0 = blockIdx.x * 4;
    for (int i = c; i < 4 * D; i += 128) {
        int gg = i / D, k = i - gg * D;
        sp[gg][k] = pooled[((size_t)l * NGR + g0 + gg) * D + k];
    }
    __syncthreads();
    float acc[4] = {0.f, 0.f, 0.f, 0.f};
    for (int k = 0; k < D; ++k) {
        float w = fcW[((size_t)l * D + k) * NC + c];
        #pragma unroll
        for (int gg = 0; gg < 4; ++gg) acc[gg] = fmaf(sp[gg][k], w, acc[gg]);
    }
    #pragma unroll
    for (int gg = 0; gg < 4; ++gg) {
        int g = g0 + gg;
        float inv = 1.0f / fmaxf((float)(off[g + 1] - off[g]), 1.0f);
        atomAdd(&out[g * NC + c], acc[gg] * inv);
    }
}

// ---------------------------------------------------------------------------
extern "C" void kernel_launch(void* const* d_in, const int* in_sizes, int n_in,
                              void* d_out, int out_size, void* d_ws, size_t ws_size,
                              hipStream_t stream) {
    const float* x       = (const float*)d_in[0];
    const int*   ei      = (const int*)d_in[1];
    const int*   batch   = (const int*)d_in[2];
    const float* W1  = (const float*)d_in[3];
    const float* b1  = (const float*)d_in[4];
    const float* g1  = (const float*)d_in[5];
    const float* be1 = (const float*)d_in[6];
    const float* W2  = (const float*)d_in[7];
    const float* b2  = (const float*)d_in[8];
    const float* bng = (const float*)d_in[9];
    const float* bnb = (const float*)d_in[10];
    const float* fcW = (const float*)d_in[11];
    const float* fcb = (const float*)d_in[12];
    float* out = (float*)d_out;

    const int N = in_sizes[0] / D;   // 50000
    const int E = in_sizes[1] / 2;   // 400000
    const int nb = (N + 255) / 256;

    u16* xbf  = (u16*)d_ws;                      // NPAD*KP
    u16* bufA = xbf + (size_t)NPAD * KP;         // NPAD*KP
    u16* bufB = bufA + (size_t)NPAD * KP;        // NPAD*KP
    u16* Wt   = bufB + (size_t)NPAD * KP;        // 10*320*KP
    float* pooled = (float*)(Wt + (size_t)10 * 320 * KP);    // 6*NGR*D
    float* stats  = pooled + (size_t)(NL + 1) * NGR * D;     // 2*KP
    float* sc1    = stats + 2 * KP;                          // 2*KP
    float* sc2    = sc1 + 2 * KP;                            // 2*KP
    int*   off    = (int*)(sc2 + 2 * KP);                    // NGR+1
    int*   rowptr = off + NGR + 1;                           // N+1
    int*   cursor = rowptr + N + 1;                          // N
    int*   col    = cursor + N;                              // E
    int*   part   = col + E;                                 // 256

    hipMemsetAsync(stats, 0, 6 * KP * sizeof(float), stream);
    offsets_kernel<<<1, 320, 0, stream>>>(batch, off, N);
    bias_init_kernel<<<(NGR * NC + 127) / 128, 128, 0, stream>>>(fcb, out);

    // ---- CSR build (once) ----
    hipMemsetAsync(cursor, 0, N * sizeof(int), stream);
    deg_kernel<<<(E + 255) / 256, 256, 0, stream>>>(ei, cursor, E);
    degpart_kernel<<<nb, 256, 0, stream>>>(cursor, part, N);
    partscan_kernel<<<1, 256, 0, stream>>>(part, nb);
    rowptr_kernel<<<nb, 256, 0, stream>>>(cursor, part, rowptr, N, E);
    hipMemsetAsync(cursor, 0, N * sizeof(int), stream);
    fill_kernel<<<(E + 255) / 256, 256, 0, stream>>>(ei, rowptr, cursor, col, E);

    // ---- precompute bf16 weights + input ----
    wcvt_kernel<<<(10 * KP * 80 + 255) / 256, 256, 0, stream>>>(W1, W2, Wt);
    xcvt_kernel<<<(NPAD * 40 + 255) / 256, 256, 0, stream>>>(x, xbf, N);

    const int gemm_blocks = 8 * RBX * 4;         // 1568
    const int nd40 = N * 40;
    float invN = 1.0f / (float)N;
    const size_t WtM = (size_t)320 * KP;

    pool_kernel<false><<<NGR, 320, 0, stream>>>(xbf, off, sc2, pooled);

    u16* g = bufA;
    u16* t = bufB;
    const u16* src = xbf;
    for (int l = 0; l < NL; ++l) {
        if (l == 0)
            gather_kernel<false><<<(nd40 + 255) / 256, 256, 0, stream>>>(src, g, rowptr, col, sc2, N);
        else
            gather_kernel<true><<<(nd40 + 255) / 256, 256, 0, stream>>>(src, g, rowptr, col, sc2, N);
        mfma_gemm_kernel<false><<<gemm_blocks, 256, 0, stream>>>(
            g, Wt + (size_t)l * WtM, b1 + l * D, sc1, t, stats, N);
        bnfin_kernel<<<1, 320, 0, stream>>>(stats, g1 + l * D, be1 + l * D, sc1, invN);
        mfma_gemm_kernel<true><<<gemm_blocks, 256, 0, stream>>>(
            t, Wt + (size_t)(NL + l) * WtM, b2 + l * D, sc1, g, stats, N);
        bnfin_kernel<<<1, 320, 0, stream>>>(stats, bng + l * D, bnb + l * D, sc2, invN);
        pool_kernel<true><<<NGR, 320, 0, stream>>>(g, off, sc2, pooled + (size_t)(l + 1) * NGR * D);
        src = g;
        u16* tmp = g; g = t; t = tmp;
    }
    readout_kernel<<<dim3(NGR / 4, NL + 1), 128, 0, stream>>>(pooled, off, fcW, out);
}

// Round 13
// 1138.952 us; speedup vs baseline: 1.1017x; 1.1017x over previous
//
#include <hip/hip_runtime.h>

#define D 300
#define KP 320
#define NPAD 50048
#define NTILES 782      // NPAD/64
#define TPB 2           // row-tiles per gemm block
#define NRB 391         // row-blocks (NTILES/TPB)
#define LRB 49          // row-blocks per XCD (8*49=392 >= 391)
#define WSTRIDE 328     // LDS k-stride (u16): 164 words, %32=4 -> 2-way banks (free)
#define NGR 256
#define NL 5
#define NC 128
#define BN_EPS 1e-5f

typedef __attribute__((ext_vector_type(8))) short bf16x8;
typedef __attribute__((ext_vector_type(4))) float f32x4;
typedef unsigned short u16;

__device__ __forceinline__ void atomAdd(float* p, float v) { unsafeAtomicAdd(p, v); }

__device__ __forceinline__ short f2bf(float f) {
    union { float f; unsigned u; } v; v.f = f;
    unsigned r = v.u + 0x7fffu + ((v.u >> 16) & 1u);   // RNE
    return (short)(r >> 16);
}
__device__ __forceinline__ float bf2f(short s) {
    union { unsigned u; float f; } v;
    v.u = ((unsigned)(u16)s) << 16;
    return v.f;
}
// HW packed f32x2 -> bf16x2 (RNE): 1 VALU op per 2 elements (round-11 win).
__device__ __forceinline__ unsigned pkbf(float a, float b) {
    unsigned r;
    asm("v_cvt_pk_bf16_f32 %0, %1, %2" : "=v"(r) : "v"(a), "v"(b));
    return r;
}
__device__ __forceinline__ bf16x8 pack8(const float* f) {
    union { unsigned u[4]; bf16x8 v; } o;
    o.u[0] = pkbf(f[0], f[1]);
    o.u[1] = pkbf(f[2], f[3]);
    o.u[2] = pkbf(f[4], f[5]);
    o.u[3] = pkbf(f[6], f[7]);
    return o.v;
}

// ---------------------------------------------------------------------------
// offsets: off[g] = lower_bound(batch, g)
// ---------------------------------------------------------------------------
__global__ void offsets_kernel(const int* __restrict__ batch, int* __restrict__ off, int N) {
    int g = threadIdx.x;
    if (g > NGR) return;
    int lo = 0, hi = N;
    while (lo < hi) {
        int mid = (lo + hi) >> 1;
        if (batch[mid] < g) lo = mid + 1; else hi = mid;
    }
    off[g] = lo;
}

// ---------------------------------------------------------------------------
// CSR build: deg histogram -> hierarchical scan -> slot fill
// ---------------------------------------------------------------------------
__global__ __launch_bounds__(256)
void deg_kernel(const int* __restrict__ ei, int* __restrict__ deg, int E) {
    int e = blockIdx.x * 256 + threadIdx.x;
    if (e < E) atomicAdd(&deg[ei[E + e]], 1);
}

__global__ __launch_bounds__(256)
void degpart_kernel(const int* __restrict__ deg, int* __restrict__ part, int N) {
    int i = blockIdx.x * 256 + threadIdx.x;
    int v = (i < N) ? deg[i] : 0;
    #pragma unroll
    for (int o = 1; o < 64; o <<= 1) v += __shfl_xor(v, o);
    __shared__ int ws[4];
    if ((threadIdx.x & 63) == 0) ws[threadIdx.x >> 6] = v;
    __syncthreads();
    if (threadIdx.x == 0) part[blockIdx.x] = ws[0] + ws[1] + ws[2] + ws[3];
}

__global__ __launch_bounds__(256)
void partscan_kernel(int* __restrict__ part, int nb) {   // 1 block; nb <= 256
    __shared__ int buf[256];
    int t = threadIdx.x;
    int v = (t < nb) ? part[t] : 0;
    buf[t] = v;
    __syncthreads();
    for (int o = 1; o < 256; o <<= 1) {
        int u = (t >= o) ? buf[t - o] : 0;
        __syncthreads();
        buf[t] += u;
        __syncthreads();
    }
    if (t < nb) part[t] = (t == 0) ? 0 : buf[t - 1];   // exclusive
}

__global__ __launch_bounds__(256)
void rowptr_kernel(const int* __restrict__ deg, const int* __restrict__ part,
                   int* __restrict__ rowptr, int N, int E) {
    __shared__ int buf[256];
    int b = blockIdx.x, t = threadIdx.x;
    int i = b * 256 + t;
    int v = (i < N) ? deg[i] : 0;
    buf[t] = v;
    __syncthreads();
    for (int o = 1; o < 256; o <<= 1) {
        int u = (t >= o) ? buf[t - o] : 0;
        __syncthreads();
        buf[t] += u;
        __syncthreads();
    }
    if (i < N) rowptr[i] = part[b] + buf[t] - v;
    if (b == 0 && t == 0) rowptr[N] = E;
}

__global__ __launch_bounds__(256)
void fill_kernel(const int* __restrict__ ei, const int* __restrict__ rowptr,
                 int* __restrict__ cursor, int* __restrict__ col, int E) {
    int e = blockIdx.x * 256 + threadIdx.x;
    if (e >= E) return;
    int src = ei[e];
    int dst = ei[E + e];
    int pos = atomicAdd(&cursor[dst], 1);
    col[rowptr[dst] + pos] = src;
}

// ---------------------------------------------------------------------------
// weight convert: Wt[mat][n (320)][k (320)] = bf16(W[k][n]); pads zero
// ---------------------------------------------------------------------------
__global__ __launch_bounds__(256)
void wcvt_kernel(const float* __restrict__ W1, const float* __restrict__ W2,
                 u16* __restrict__ Wt) {
    int idx = blockIdx.x * 256 + threadIdx.x;
    if (idx >= 10 * KP * 80) return;
    int n4 = idx % 80;
    int k = (idx / 80) % KP;
    int mat = idx / (80 * KP);
    const float* Wsrc = (mat < NL) ? (W1 + (size_t)mat * D * D) : (W2 + (size_t)(mat - NL) * D * D);
    float4 w = make_float4(0.f, 0.f, 0.f, 0.f);
    if (k < D && n4 < 75) w = *(const float4*)(Wsrc + (size_t)k * D + n4 * 4);
    size_t base = ((size_t)mat * 320 + n4 * 4) * KP + k;
    Wt[base]          = (u16)f2bf(w.x);
    Wt[base + KP]     = (u16)f2bf(w.y);
    Wt[base + 2 * KP] = (u16)f2bf(w.z);
    Wt[base + 3 * KP] = (u16)f2bf(w.w);
}

// ---------------------------------------------------------------------------
// x convert: xbf[row][c] = bf16(x[row][c]), pads (c>=300, row>=N) zero
// ---------------------------------------------------------------------------
__global__ __launch_bounds__(256)
void xcvt_kernel(const float* __restrict__ x, u16* __restrict__ xbf, int N) {
    int idx = blockIdx.x * 256 + threadIdx.x;
    if (idx >= NPAD * 40) return;
    int row = idx / 40;
    int c8 = (idx - row * 40) * 8;
    short o[8];
    #pragma unroll
    for (int i = 0; i < 8; ++i) {
        int c = c8 + i;
        float f = (row < N && c < D) ? x[(size_t)row * D + c] : 0.f;
        o[i] = f2bf(f);
    }
    *(bf16x8*)(xbf + (size_t)row * KP + c8) = *(bf16x8*)o;
}

// ---------------------------------------------------------------------------
// gather with fused BN2+ReLU on source rows; edge loop unrolled x4 (MLP).
// ---------------------------------------------------------------------------
template<bool APPLY>
__global__ __launch_bounds__(256)
void gather_kernel(const u16* __restrict__ H, u16* __restrict__ Z,
                   const int* __restrict__ rowptr, const int* __restrict__ col,
                   const float* __restrict__ scsh, int N) {
    int idx = blockIdx.x * 256 + threadIdx.x;
    if (idx >= N * 40) return;
    int node = idx / 40;
    int c8 = (idx - node * 40) * 8;
    float sc[8], sh[8];
    if (APPLY) {
        #pragma unroll
        for (int i = 0; i < 8; ++i) { sc[i] = scsh[c8 + i]; sh[i] = scsh[KP + c8 + i]; }
    }
    int s = rowptr[node], e = rowptr[node + 1];
    bf16x8 v = *(const bf16x8*)(H + (size_t)node * KP + c8);
    float acc[8];
    #pragma unroll
    for (int i = 0; i < 8; ++i) {
        float f = bf2f(v[i]);
        acc[i] = APPLY ? fmaxf(fmaf(f, sc[i], sh[i]), 0.f) : f;
    }
    int j = s;
    for (; j + 4 <= e; j += 4) {           // 4 row-loads in flight
        int s0 = col[j], s1 = col[j + 1], s2 = col[j + 2], s3 = col[j + 3];
        bf16x8 w0 = *(const bf16x8*)(H + (size_t)s0 * KP + c8);
        bf16x8 w1 = *(const bf16x8*)(H + (size_t)s1 * KP + c8);
        bf16x8 w2 = *(const bf16x8*)(H + (size_t)s2 * KP + c8);
        bf16x8 w3 = *(const bf16x8*)(H + (size_t)s3 * KP + c8);
        #pragma unroll
        for (int i = 0; i < 8; ++i) {
            float f0 = bf2f(w0[i]), f1 = bf2f(w1[i]);
            float f2 = bf2f(w2[i]), f3 = bf2f(w3[i]);
            if (APPLY) {
                f0 = fmaxf(fmaf(f0, sc[i], sh[i]), 0.f);
                f1 = fmaxf(fmaf(f1, sc[i], sh[i]), 0.f);
                f2 = fmaxf(fmaf(f2, sc[i], sh[i]), 0.f);
                f3 = fmaxf(fmaf(f3, sc[i], sh[i]), 0.f);
            }
            acc[i] += (f0 + f1) + (f2 + f3);
        }
    }
    for (; j < e; ++j) {
        int s0 = col[j];
        bf16x8 w0 = *(const bf16x8*)(H + (size_t)s0 * KP + c8);
        #pragma unroll
        for (int i = 0; i < 8; ++i) {
            float f0 = bf2f(w0[i]);
            acc[i] += APPLY ? fmaxf(fmaf(f0, sc[i], sh[i]), 0.f) : f0;
        }
    }
    *(bf16x8*)(Z + (size_t)node * KP + c8) = pack8(acc);
}

// ---------------------------------------------------------------------------
// pool with optional fused BN2+ReLU; one block per graph, coalesced rows.
// ---------------------------------------------------------------------------
template<bool APPLY>
__global__ __launch_bounds__(320)
void pool_kernel(const u16* __restrict__ H, const int* __restrict__ off,
                 const float* __restrict__ scsh, float* __restrict__ pooled_l) {
    __shared__ float red[8][KP];
    int t = threadIdx.x;
    int g = blockIdx.x;
    int rq = t / 40;
    int c8 = (t - rq * 40) * 8;
    float sc[8], sh[8];
    if (APPLY) {
        #pragma unroll
        for (int i = 0; i < 8; ++i) { sc[i] = scsh[c8 + i]; sh[i] = scsh[KP + c8 + i]; }
    }
    int r0 = off[g], r1 = off[g + 1];
    float a[8] = {};
    for (int r = r0 + rq; r < r1; r += 8) {
        bf16x8 v = *(const bf16x8*)(H + (size_t)r * KP + c8);
        #pragma unroll
        for (int i = 0; i < 8; ++i) {
            float f = bf2f(v[i]);
            a[i] += APPLY ? fmaxf(fmaf(f, sc[i], sh[i]), 0.f) : f;
        }
    }
    #pragma unroll
    for (int i = 0; i < 8; ++i) red[rq][c8 + i] = a[i];
    __syncthreads();
    int c = t;
    if (c < D) {
        float s = 0.f;
        #pragma unroll
        for (int j = 0; j < 8; ++j) s += red[j][c];
        pooled_l[g * D + c] = s;
    }
}

// ---------------------------------------------------------------------------
// Persistent-W MFMA GEMM, quarter-INNERMOST XCD-interleaved decode:
//   xcd = bid&7, j = bid>>3, lr = j>>2, quarter = j&3, rowblock = lr*8+xcd.
// The 4 quarter-blocks sharing one 80KB A-slab are dispatch-adjacent on the
// SAME XCD -> co-resident -> A fetched from L3 once (round-11 failure was
// quarter-OUTER: re-reads ~50 blocks apart, beyond residency; FETCH stayed
// 52MB). No cross-tile A prefetch (round-11 VGPR 164 -> occupancy 8.6%
// regression); packed v_cvt_pk_bf16_f32 conversions kept (VALU 24%->11%).
// Zero barriers in the tile loop; W-slab staged once per block.
// ---------------------------------------------------------------------------
template<bool APPLY>
__global__ __launch_bounds__(256)
void mfma_gemm_kernel(const u16* __restrict__ Abf, const u16* __restrict__ Wt,
                      const float* __restrict__ bias, const float* __restrict__ scsh,
                      u16* __restrict__ Cbf, float* __restrict__ stats, int Nreal) {
    const int bid = blockIdx.x;
    const int xcd = bid & 7;
    const int j = bid >> 3;
    const int quarter = j & 3;
    const int rowblock = (j >> 2) * 8 + xcd;
    if (rowblock >= NRB) return;           // uniform; 4 idle blocks
    const int nBase = quarter * 80;

    __shared__ u16 Ws[80 * WSTRIDE];       // 52.5 KB
    __shared__ float lsum[80], lsq[80];
    const int tid = threadIdx.x;

    {   // stage W quarter once: 80 n-rows x 40 bf16x8 units
        const u16* src = Wt + (size_t)nBase * KP;
        for (int unit = tid; unit < 80 * 40; unit += 256) {
            int n = unit / 40, kg = unit - n * 40;
            *(bf16x8*)&Ws[n * WSTRIDE + kg * 8] =
                *(const bf16x8*)(src + (size_t)n * KP + kg * 8);
        }
    }
    if (tid < 80) { lsum[tid] = 0.f; lsq[tid] = 0.f; }
    __syncthreads();                       // barrier 1 of 2

    const int wave = tid >> 6, lane = tid & 63;
    const int quad = lane >> 4, l16 = lane & 15;
    const int tile0 = rowblock * TPB;

    for (int t = 0; t < TPB; ++t) {
        const int mBase = (tile0 + t) * 64 + wave * 16;
        const u16* arow = Abf + (size_t)(mBase + l16) * KP + quad * 8;

        bf16x8 a[10];
        #pragma unroll
        for (int kc = 0; kc < 10; ++kc) a[kc] = *(const bf16x8*)(arow + kc * 32);
        if (APPLY) {
            #pragma unroll
            for (int kc = 0; kc < 10; ++kc) {
                const float* sp = scsh + kc * 32 + quad * 8;
                float4 s0 = *(const float4*)sp;
                float4 s1 = *(const float4*)(sp + 4);
                float4 h0 = *(const float4*)(sp + KP);
                float4 h1 = *(const float4*)(sp + KP + 4);
                float sc[8] = {s0.x, s0.y, s0.z, s0.w, s1.x, s1.y, s1.z, s1.w};
                float sh[8] = {h0.x, h0.y, h0.z, h0.w, h1.x, h1.y, h1.z, h1.w};
                float f[8];
                #pragma unroll
                for (int i = 0; i < 8; ++i)
                    f[i] = fmaxf(fmaf(bf2f(a[kc][i]), sc[i], sh[i]), 0.f);
                a[kc] = pack8(f);
            }
        }

        f32x4 acc[5] = {};
        #pragma unroll
        for (int kc = 0; kc < 10; ++kc) {
            #pragma unroll
            for (int nt = 0; nt < 5; ++nt) {
                bf16x8 b = *(const bf16x8*)&Ws[(nt * 16 + l16) * WSTRIDE + kc * 32 + quad * 8];
                acc[nt] = __builtin_amdgcn_mfma_f32_16x16x32_bf16(a[kc], b, acc[nt], 0, 0, 0);
            }
        }

        // epilogue
        const int rbase = mBase + quad * 4;
        #pragma unroll
        for (int nt = 0; nt < 5; ++nt) {
            int nl = nt * 16 + l16;
            int colg = nBase + nl;
            if (colg >= D) continue;
            float bia = bias[colg];
            float v0 = acc[nt][0] + bia, v1 = acc[nt][1] + bia;
            float v2 = acc[nt][2] + bia, v3 = acc[nt][3] + bia;
            float s = 0.f, q = 0.f;
            bool ok0 = rbase + 0 < Nreal, ok1 = rbase + 1 < Nreal;
            bool ok2 = rbase + 2 < Nreal, ok3 = rbase + 3 < Nreal;
            if (ok0) { s += v0; q = fmaf(v0, v0, q); }
            if (ok1) { s += v1; q = fmaf(v1, v1, q); }
            if (ok2) { s += v2; q = fmaf(v2, v2, q); }
            if (ok3) { s += v3; q = fmaf(v3, v3, q); }
            unsigned pa = pkbf(v0, v1), pb = pkbf(v2, v3);
            Cbf[(size_t)(rbase + 0) * KP + colg] = ok0 ? (u16)pa : (u16)0;
            Cbf[(size_t)(rbase + 1) * KP + colg] = ok1 ? (u16)(pa >> 16) : (u16)0;
            Cbf[(size_t)(rbase + 2) * KP + colg] = ok2 ? (u16)pb : (u16)0;
            Cbf[(size_t)(rbase + 3) * KP + colg] = ok3 ? (u16)(pb >> 16) : (u16)0;
            s += __shfl_xor(s, 16); s += __shfl_xor(s, 32);
            q += __shfl_xor(q, 16); q += __shfl_xor(q, 32);
            if (quad == 0) { atomicAdd(&lsum[nl], s); atomicAdd(&lsq[nl], q); }
        }
    }
    __syncthreads();                       // barrier 2 of 2
    if (tid < 80) {
        int colg = nBase + tid;
        if (colg < D) {
            atomAdd(&stats[colg], lsum[tid]);
            atomAdd(&stats[KP + colg], lsq[tid]);
        }
    }
}

// ---------------------------------------------------------------------------
// BN finalize; self-zeroes stats for the next GEMM
// ---------------------------------------------------------------------------
__global__ void bnfin_kernel(float* __restrict__ sums, const float* __restrict__ g,
                             const float* __restrict__ be, float* __restrict__ scsh, float invN) {
    int c = threadIdx.x;
    if (c >= D) return;
    float mu = sums[c] * invN;
    float var = sums[KP + c] * invN - mu * mu;
    float s = g[c] / sqrtf(var + BN_EPS);
    scsh[c] = s;
    scsh[KP + c] = fmaf(-mu, s, be[c]);
    sums[c] = 0.f;
    sums[KP + c] = 0.f;
}

// ---------------------------------------------------------------------------
// readout
// ---------------------------------------------------------------------------
__global__ __launch_bounds__(128)
void bias_init_kernel(const float* __restrict__ fcb, float* __restrict__ out) {
    int i = blockIdx.x * 128 + threadIdx.x;
    if (i >= NGR * NC) return;
    int c = i & (NC - 1);
    float s = 0.f;
    for (int l = 0; l <= NL; ++l) s += fcb[l * NC + c];
    out[i] = s;
}

__global__ __launch_bounds__(128)
void readout_kernel(const float* __restrict__ pooled, const int* __restrict__ off,
                    const float* __restrict__ fcW, float* __restrict__ out) {
    __shared__ float sp[4][D];
    int c = threadIdx.x;
    int l = blockIdx.y;
    int g0 = blockIdx.x * 4;
    for (int i = c; i < 4 * D; i += 128) {
        int gg = i / D, k = i - gg * D;
        sp[gg][k] = pooled[((size_t)l * NGR + g0 + gg) * D + k];
    }
    __syncthreads();
    float acc[4] = {0.f, 0.f, 0.f, 0.f};
    for (int k = 0; k < D; ++k) {
        float w = fcW[((size_t)l * D + k) * NC + c];
        #pragma unroll
        for (int gg = 0; gg < 4; ++gg) acc[gg] = fmaf(sp[gg][k], w, acc[gg]);
    }
    #pragma unroll
    for (int gg = 0; gg < 4; ++gg) {
        int g = g0 + gg;
        float inv = 1.0f / fmaxf((float)(off[g + 1] - off[g]), 1.0f);
        atomAdd(&out[g * NC + c], acc[gg] * inv);
    }
}

// ---------------------------------------------------------------------------
extern "C" void kernel_launch(void* const* d_in, const int* in_sizes, int n_in,
                              void* d_out, int out_size, void* d_ws, size_t ws_size,
                              hipStream_t stream) {
    const float* x       = (const float*)d_in[0];
    const int*   ei      = (const int*)d_in[1];
    const int*   batch   = (const int*)d_in[2];
    const float* W1  = (const float*)d_in[3];
    const float* b1  = (const float*)d_in[4];
    const float* g1  = (const float*)d_in[5];
    const float* be1 = (const float*)d_in[6];
    const float* W2  = (const float*)d_in[7];
    const float* b2  = (const float*)d_in[8];
    const float* bng = (const float*)d_in[9];
    const float* bnb = (const float*)d_in[10];
    const float* fcW = (const float*)d_in[11];
    const float* fcb = (const float*)d_in[12];
    float* out = (float*)d_out;

    const int N = in_sizes[0] / D;   // 50000
    const int E = in_sizes[1] / 2;   // 400000
    const int nb = (N + 255) / 256;

    u16* xbf  = (u16*)d_ws;                      // NPAD*KP
    u16* bufA = xbf + (size_t)NPAD * KP;         // NPAD*KP
    u16* bufB = bufA + (size_t)NPAD * KP;        // NPAD*KP
    u16* Wt   = bufB + (size_t)NPAD * KP;        // 10*320*KP
    float* pooled = (float*)(Wt + (size_t)10 * 320 * KP);    // 6*NGR*D
    float* stats  = pooled + (size_t)(NL + 1) * NGR * D;     // 2*KP
    float* sc1    = stats + 2 * KP;                          // 2*KP
    float* sc2    = sc1 + 2 * KP;                            // 2*KP
    int*   off    = (int*)(sc2 + 2 * KP);                    // NGR+1
    int*   rowptr = off + NGR + 1;                           // N+1
    int*   cursor = rowptr + N + 1;                          // N
    int*   col    = cursor + N;                              // E
    int*   part   = col + E;                                 // 256

    hipMemsetAsync(stats, 0, 6 * KP * sizeof(float), stream);
    offsets_kernel<<<1, 320, 0, stream>>>(batch, off, N);
    bias_init_kernel<<<(NGR * NC + 127) / 128, 128, 0, stream>>>(fcb, out);

    // ---- CSR build (once) ----
    hipMemsetAsync(cursor, 0, N * sizeof(int), stream);
    deg_kernel<<<(E + 255) / 256, 256, 0, stream>>>(ei, cursor, E);
    degpart_kernel<<<nb, 256, 0, stream>>>(cursor, part, N);
    partscan_kernel<<<1, 256, 0, stream>>>(part, nb);
    rowptr_kernel<<<nb, 256, 0, stream>>>(cursor, part, rowptr, N, E);
    hipMemsetAsync(cursor, 0, N * sizeof(int), stream);
    fill_kernel<<<(E + 255) / 256, 256, 0, stream>>>(ei, rowptr, cursor, col, E);

    // ---- precompute bf16 weights + input ----
    wcvt_kernel<<<(10 * KP * 80 + 255) / 256, 256, 0, stream>>>(W1, W2, Wt);
    xcvt_kernel<<<(NPAD * 40 + 255) / 256, 256, 0, stream>>>(x, xbf, N);

    const int gemm_blocks = 8 * LRB * 4;         // 1568
    const int nd40 = N * 40;
    float invN = 1.0f / (float)N;
    const size_t WtM = (size_t)320 * KP;

    pool_kernel<false><<<NGR, 320, 0, stream>>>(xbf, off, sc2, pooled);

    u16* g = bufA;
    u16* t = bufB;
    const u16* src = xbf;
    for (int l = 0; l < NL; ++l) {
        if (l == 0)
            gather_kernel<false><<<(nd40 + 255) / 256, 256, 0, stream>>>(src, g, rowptr, col, sc2, N);
        else
            gather_kernel<true><<<(nd40 + 255) / 256, 256, 0, stream>>>(src, g, rowptr, col, sc2, N);
        mfma_gemm_kernel<false><<<gemm_blocks, 256, 0, stream>>>(
            g, Wt + (size_t)l * WtM, b1 + l * D, sc1, t, stats, N);
        bnfin_kernel<<<1, 320, 0, stream>>>(stats, g1 + l * D, be1 + l * D, sc1, invN);
        mfma_gemm_kernel<true><<<gemm_blocks, 256, 0, stream>>>(
            t, Wt + (size_t)(NL + l) * WtM, b2 + l * D, sc1, g, stats, N);
        bnfin_kernel<<<1, 320, 0, stream>>>(stats, bng + l * D, bnb + l * D, sc2, invN);
        pool_kernel<true><<<NGR, 320, 0, stream>>>(g, off, sc2, pooled + (size_t)(l + 1) * NGR * D);
        src = g;
        u16* tmp = g; g = t; t = tmp;
    }
    readout_kernel<<<dim3(NGR / 4, NL + 1), 128, 0, stream>>>(pooled, off, fcW, out);
}